// Round 7
// baseline (504.510 us; speedup 1.0000x reference)
//
#include <hip/hip_runtime.h>
#include <stdint.h>

// ---------------------------------------------------------------------------
// Dual attention (DANet): pos attention + channel attention, fused pipeline.
// B=8, C=512, CQ=64, H=W=64, HW=4096.  All GEMMs bf16 MFMA 16x16x32, fp32 acc.
//
// pos_out[c,j] = sum_i v'[c,i] * exp(e[i,j]),  v' = (Wv x + b) * rcp_l[i],
//   rcp_l[i] = 1 / sum_j exp(e[i,j])   (no max subtraction: |e| <~ 13)
// LOG2E folded into wq/pq_b at convert time -> exp2 direct.
//
// v8: ALL MFMA operand streams fragment/row-linear:
//   q_lin [b][i/16][ks 2][lane-frag 512]      (1KB A-frag bursts)
//   kT    [b][j/16][ks 2][lane-frag 512]      (1KB B-frag bursts, NEW)
//   cvT   [b][4096][64]                       (linear A-staging for coT GEMM)
//   vP    [b][ib 32][ct 32][ks 4][lane-frag]  (1KB V-frag bursts)
//   qkv + cqck projections merged into ONE GEMM ([320][512] weights x xT).
//   rowsum: LDS-free B-frag streaming (2-wave blocks, VALU/trans-bound).
// pos_attn = round-4 structure EXACT (NO setprio - block co-phase controls
//   the vP L2 working set; only Ks staging source remapped to frag-linear).
// NOTE: pos_attn register budget is EXACTLY 64 arch + 64 acc = 128 = the
// 4-wave/SIMD boundary.  Do not add live state to pos_attn.
// ---------------------------------------------------------------------------

#define LOG2E 1.44269504088896340736f

typedef __attribute__((ext_vector_type(8))) __bf16 bf16x8;
typedef __attribute__((ext_vector_type(4))) float floatx4;
typedef __attribute__((ext_vector_type(2))) float floatx2;
typedef __attribute__((ext_vector_type(2))) unsigned int uint2v;

static __device__ __forceinline__ unsigned short f2bf(float f) {
    union { float f; uint32_t u; } v; v.f = f;
    uint32_t r = v.u + 0x7fffu + ((v.u >> 16) & 1u);   // RNE
    return (unsigned short)(r >> 16);
}

// pack two fp32 -> bf16x2 (round-half-up: +0x8000, take high16 via v_perm)
static __device__ __forceinline__ unsigned int pack_bf16(float a, float b) {
    union { float f; uint32_t u; } x, y; x.f = a; y.f = b;
    return __builtin_amdgcn_perm(y.u + 0x8000u, x.u + 0x8000u, 0x07060302u);
}

// ---------------------------------------------------------------------------
// Generic TN GEMM: C[m,n] = (sum_k A[m,k]*B[n,k] + bias_m[m] + bias_n[n])
//                  * scale_n[n].   A,B bf16 K-contiguous. BK=64.
// SPECIAL=1 (VTILE): write C in pos_attn's V-fragment-linear layout
//   idx = (n>>7)*65536 + (m>>4)*2048 + ((n>>5)&3)*512 + (m&15)*32
//       + ((n>>3)&3)*8 + (n&7)     (m = c, n = i)
// SPECIAL=2 (merged projection): m = spatial i, n = output channel [0,320):
//   n<64   -> q_lin frag-linear
//   n<128  -> kT frag-linear (kk = n-64)
//   n<192  -> cvT row-major lda 64
//   n>=192 -> cqck (buffer C2): idx = (n-192)*4096 + m
// ---------------------------------------------------------------------------
template<int BM, int BN, bool OUT_BF16, bool ATOMIC, int SPECIAL = 0>
__global__ __launch_bounds__(256) void tn_gemm(
    const unsigned short* __restrict__ A, int lda, long sA,
    const unsigned short* __restrict__ B, int ldb, long sB,
    void* __restrict__ C, int ldc, long sC,
    void* __restrict__ C2, long sC2,
    const float* __restrict__ bias_m, const float* __restrict__ bias_n,
    const float* __restrict__ scale_n, long sScale,
    int K, int kchunks)
{
    constexpr int PK = 72;                 // 64 + 8 pad
    __shared__ unsigned short As[BM * PK];
    __shared__ unsigned short Bs[BN * PK];
    const int bz = blockIdx.z;
    const int b  = bz / kchunks;
    const int kc = bz % kchunks;
    const int m0 = blockIdx.y * BM;
    const int n0 = blockIdx.x * BN;
    const unsigned short* Ab = A + (long)b * sA + (long)m0 * lda + (long)kc * K;
    const unsigned short* Bb = B + (long)b * sB + (long)n0 * ldb + (long)kc * K;
    const int tid = threadIdx.x;
    const int lane = tid & 63, wave = tid >> 6;
    const int l15 = lane & 15, quad = lane >> 4;
    constexpr int NT  = BN / 16;
    constexpr int MPW = BM / 64;
    constexpr int AL  = BM / 32;
    constexpr int BL  = BN / 32;

    const floatx4 vz = {0.f, 0.f, 0.f, 0.f};
    floatx4 acc[MPW][NT];
    for (int i = 0; i < MPW; ++i) for (int j = 0; j < NT; ++j) acc[i][j] = vz;

    const int nK = K >> 6;
    for (int k0 = 0; k0 < nK; ++k0) {
        floatx4 ar[AL], br[BL];
#pragma unroll
        for (int L = 0; L < AL; ++L) {
            int flat = L * 2048 + tid * 8;
            ar[L] = *(const floatx4*)(Ab + (long)(flat >> 6) * lda + (k0 << 6) + (flat & 63));
        }
#pragma unroll
        for (int L = 0; L < BL; ++L) {
            int flat = L * 2048 + tid * 8;
            br[L] = *(const floatx4*)(Bb + (long)(flat >> 6) * ldb + (k0 << 6) + (flat & 63));
        }
        __syncthreads();
#pragma unroll
        for (int L = 0; L < AL; ++L) {
            int flat = L * 2048 + tid * 8;
            *(floatx4*)&As[(flat >> 6) * PK + (flat & 63)] = ar[L];
        }
#pragma unroll
        for (int L = 0; L < BL; ++L) {
            int flat = L * 2048 + tid * 8;
            *(floatx4*)&Bs[(flat >> 6) * PK + (flat & 63)] = br[L];
        }
        __syncthreads();
#pragma unroll
        for (int ks = 0; ks < 2; ++ks) {
            bf16x8 af[MPW];
#pragma unroll
            for (int mi = 0; mi < MPW; ++mi)
                af[mi] = *(const bf16x8*)&As[((wave * MPW + mi) * 16 + l15) * PK + ks * 32 + quad * 8];
#pragma unroll
            for (int nt = 0; nt < NT; ++nt) {
                bf16x8 bf = *(const bf16x8*)&Bs[(nt * 16 + l15) * PK + ks * 32 + quad * 8];
#pragma unroll
                for (int mi = 0; mi < MPW; ++mi)
                    acc[mi][nt] = __builtin_amdgcn_mfma_f32_16x16x32_bf16(af[mi], bf, acc[mi][nt], 0, 0, 0);
            }
        }
    }
    // epilogue (C/D layout: col = lane&15, row = quad*4 + r)
#pragma unroll
    for (int mi = 0; mi < MPW; ++mi) {
        const int mb = m0 + (wave * MPW + mi) * 16 + quad * 4;
#pragma unroll
        for (int nt = 0; nt < NT; ++nt) {
            const int n = n0 + nt * 16 + l15;
            const float bn = bias_n ? bias_n[n] : 0.f;
            const float cs = scale_n ? scale_n[(long)b * sScale + n] : 1.f;
            floatx4 a = acc[mi][nt];
#pragma unroll
            for (int r = 0; r < 4; ++r) {
                const int m = mb + r;
                float v = (a[r] + (bias_m ? bias_m[m] : 0.f) + bn) * cs;
                if (SPECIAL == 2) {
                    unsigned short* dp;
                    long idx2;
                    if (n < 64) {
                        dp = (unsigned short*)C;
                        idx2 = (long)b * sC + ((long)(m >> 4) * 1024 + (n >> 5) * 512
                             + (m & 15) * 32 + ((n >> 3) & 3) * 8 + (n & 7));
                    } else if (n < 128) {
                        const int kk = n - 64;
                        dp = (unsigned short*)C;
                        idx2 = (long)b * sC + 262144 + ((long)(m >> 4) * 1024 + (kk >> 5) * 512
                             + (m & 15) * 32 + ((kk >> 3) & 3) * 8 + (kk & 7));
                    } else if (n < 192) {
                        dp = (unsigned short*)C;
                        idx2 = (long)b * sC + 524288 + (long)m * 64 + (n - 128);
                    } else {
                        dp = (unsigned short*)C2;
                        idx2 = (long)b * sC2 + (long)(n - 192) * 4096 + m;
                    }
                    dp[idx2] = f2bf(v);
                } else {
                    long idx;
                    if (SPECIAL == 1)
                        idx = (long)b * sC + ((long)(n >> 7) * 65536 + (m >> 4) * 2048
                            + ((n >> 5) & 3) * 512 + (m & 15) * 32 + ((n >> 3) & 3) * 8 + (n & 7));
                    else
                        idx = (long)b * sC + (long)m * ldc + n;
                    if (ATOMIC)         atomicAdd((float*)C + idx, v);
                    else if (OUT_BF16)  ((unsigned short*)C)[idx] = f2bf(v);
                    else                ((float*)C)[idx] = v;
                }
            }
        }
    }
}

// ---------------------------------------------------------------------------
// rcp_l[b,i] = 1 / sum_j exp2(E'[i,j]).  v8: LDS-FREE streaming.
// q from q_lin, K from frag-linear kT: every load is a dense 1KB burst.
// Block = 128 threads (2 waves), each wave 32 i-rows (2 A-frag pairs);
// loop 256 j-tiles x 2 MFMA, exp2-accumulate per lane, 16-lane reduce.
// grid (8,64) = 512 blocks, no barriers, ~70 VGPR -> 4 waves/SIMD.
// ---------------------------------------------------------------------------
__global__ __launch_bounds__(128, 4) void rowsum_kernel(
    const unsigned short* __restrict__ qkvT, float* __restrict__ rcl)
{
    const int b  = blockIdx.x;
    const int i0 = blockIdx.y * 64;
    const unsigned short* qv = qkvT + (long)b * 786432;            // q_lin
    const unsigned short* kf = qkvT + (long)b * 786432 + 262144;   // kT frags
    const int tid = threadIdx.x, lane = tid & 63, wave = tid >> 6;
    const int l15 = lane & 15, quad = lane >> 4;
    const int lfrag = l15 * 32 + quad * 8;

    bf16x8 af[2][2];   // [i-tile][ks]
#pragma unroll
    for (int t = 0; t < 2; ++t)
#pragma unroll
        for (int ks = 0; ks < 2; ++ks)
            af[t][ks] = *(const bf16x8*)(qv + (long)((i0 >> 4) + wave * 2 + t) * 1024
                                             + ks * 512 + lfrag);

    float rs[2][4] = {{0.f,0.f,0.f,0.f},{0.f,0.f,0.f,0.f}};
    const floatx4 vz = {0.f, 0.f, 0.f, 0.f};
    for (int jt = 0; jt < 256; ++jt) {
        bf16x8 b0 = *(const bf16x8*)(kf + jt * 1024 + lfrag);
        bf16x8 b1 = *(const bf16x8*)(kf + jt * 1024 + 512 + lfrag);
#pragma unroll
        for (int t = 0; t < 2; ++t) {
            floatx4 e = __builtin_amdgcn_mfma_f32_16x16x32_bf16(af[t][0], b0, vz, 0, 0, 0);
            e = __builtin_amdgcn_mfma_f32_16x16x32_bf16(af[t][1], b1, e, 0, 0, 0);
#pragma unroll
            for (int r = 0; r < 4; ++r) rs[t][r] += exp2f(e[r]);
        }
    }
#pragma unroll
    for (int t = 0; t < 2; ++t)
#pragma unroll
        for (int r = 0; r < 4; ++r) {
            float v = rs[t][r];
            v += __shfl_xor(v, 1); v += __shfl_xor(v, 2);
            v += __shfl_xor(v, 4); v += __shfl_xor(v, 8);
            if (l15 == 0)
                rcl[(long)b * 4096 + i0 + (wave * 2 + t) * 16 + quad * 4 + r] = 1.0f / v;
        }
}

// ---------------------------------------------------------------------------
// Fused position attention + channel-output epilogue (round-4 structure).
// Block = (batch, j-tile 64), 512 threads (8 waves); c-tile = 512 (full).
// Per i-iter (128): ONE barrier. Region: PV(ib) reads Ps[cur] || E(ib+1)
// writes Ps[1-cur].  E: q frags = 1KB bursts; Ks staged in LDS from the
// frag-linear kT (contiguous 8KB read, scatter LDS write, one-time).
// PV: V frags = 1KB bursts from tiled vP (L2-shared across blocks).
// NO setprio: block co-phase controls the vP L2 working set (round-5 lesson).
// Epilogue adds wco . coT^T (K=64) + co_b, writes out once.
// ---------------------------------------------------------------------------
__global__ __launch_bounds__(512, 4) void pos_attn_kernel(
    const unsigned short* __restrict__ qkvT, const unsigned short* __restrict__ vP,
    const unsigned short* __restrict__ wco, const unsigned short* __restrict__ coT,
    const float* __restrict__ co_b, float* __restrict__ out)
{
    __shared__ unsigned short Ks[64 * 72];
    __shared__ unsigned short Ps[2][64 * 136];   // P^T [j][i 128], +8 pad
    const int b  = blockIdx.x;
    const int j0 = blockIdx.y * 64;
    const unsigned short* qb = qkvT + (long)b * 786432;                        // q_lin
    const unsigned short* kf = qkvT + (long)b * 786432 + 262144 + (long)(j0 >> 4) * 1024; // kT frags
    const unsigned short* vb = vP + (long)b * 512 * 4096;
    const int tid = threadIdx.x, lane = tid & 63, wave = tid >> 6;
    const int l15 = lane & 15, quad = lane >> 4;
    const int il = wave * 16 + quad * 4;
    const int lfrag = (l15 * 4 + quad) * 8;      // per-lane offset in a 1KB frag
    const int vfrag = l15 * 32 + quad * 8;       // per-lane offset in a V frag tile

    // stage Ks: 4 consecutive kT frag-tiles = 8KB contiguous; scatter-write
    // to the [row][col] (stride 72) layout the E-phase reads.
    {
        int g = tid * 8;
        int row = ((g >> 10) << 4) | ((g >> 5) & 15);
        int col = ((g >> 9) & 1) * 32 + ((g >> 3) & 3) * 8;
        *(floatx4*)&Ks[row * 72 + col] = *(const floatx4*)(kf + g);
    }
    const floatx4 vz = {0.f, 0.f, 0.f, 0.f};
    floatx4 oacc[4][4];
#pragma unroll
    for (int mi = 0; mi < 4; ++mi) for (int nt = 0; nt < 4; ++nt) oacc[mi][nt] = vz;
    __syncthreads();

    // E phase for i-block ib -> Ps[buf]
    auto e_phase = [&](int ib, int buf) {
        const unsigned short* qr = qb + (long)(ib * 8 + wave) * 1024;
        bf16x8 a0 = *(const bf16x8*)(qr + lfrag);
        bf16x8 a1 = *(const bf16x8*)(qr + 512 + lfrag);
        floatx4 e[4];
#pragma unroll
        for (int nt = 0; nt < 4; ++nt) e[nt] = vz;
#pragma unroll
        for (int nt = 0; nt < 4; ++nt) {
            bf16x8 bf = *(const bf16x8*)&Ks[(nt * 16 + l15) * 72 + quad * 8];
            e[nt] = __builtin_amdgcn_mfma_f32_16x16x32_bf16(a0, bf, e[nt], 0, 0, 0);
        }
#pragma unroll
        for (int nt = 0; nt < 4; ++nt) {
            bf16x8 bf = *(const bf16x8*)&Ks[(nt * 16 + l15) * 72 + 32 + quad * 8];
            e[nt] = __builtin_amdgcn_mfma_f32_16x16x32_bf16(a1, bf, e[nt], 0, 0, 0);
        }
#pragma unroll
        for (int nt = 0; nt < 4; ++nt) {
            uint2v p;
            p.x = pack_bf16(exp2f(e[nt][0]), exp2f(e[nt][1]));
            p.y = pack_bf16(exp2f(e[nt][2]), exp2f(e[nt][3]));
            *(uint2v*)&Ps[buf][(nt * 16 + l15) * 136 + il] = p;
        }
    };

    e_phase(0, 0);
    __syncthreads();

    for (int ib = 0; ib < 32; ++ib) {
        const int cur = ib & 1;
        // --- out += V' * P (m: 64 c-rows/wave, n=j 64, k=i 128) ---
        const unsigned short* vt = vb + (long)ib * 65536 + (wave * 4) * 2048 + vfrag;
#pragma unroll
        for (int ks = 0; ks < 4; ++ks) {
            bf16x8 af[4];
#pragma unroll
            for (int mi = 0; mi < 4; ++mi)
                af[mi] = *(const bf16x8*)(vt + mi * 2048 + ks * 512);
#pragma unroll
            for (int nt = 0; nt < 4; ++nt) {
                bf16x8 bf = *(const bf16x8*)&Ps[cur][(nt * 16 + l15) * 136 + ks * 32 + quad * 8];
#pragma unroll
                for (int mi = 0; mi < 4; ++mi)
                    oacc[mi][nt] = __builtin_amdgcn_mfma_f32_16x16x32_bf16(af[mi], bf, oacc[mi][nt], 0, 0, 0);
            }
        }
        if (ib < 31) e_phase(ib + 1, 1 - cur);
        __syncthreads();
    }

    // --- fused channel output: out += wco . coT^T (m=c, n=j, k=q 64) ---
    const unsigned short* cob = coT + ((long)b * 4096 + j0) * 64;
#pragma unroll
    for (int ks = 0; ks < 2; ++ks) {
        bf16x8 aw[4];
#pragma unroll
        for (int mi = 0; mi < 4; ++mi)
            aw[mi] = *(const bf16x8*)(wco + (long)((wave * 4 + mi) * 16 + l15) * 64 + ks * 32 + quad * 8);
#pragma unroll
        for (int nt = 0; nt < 4; ++nt) {
            bf16x8 bf = *(const bf16x8*)(cob + (long)(nt * 16 + l15) * 64 + ks * 32 + quad * 8);
#pragma unroll
            for (int mi = 0; mi < 4; ++mi)
                oacc[mi][nt] = __builtin_amdgcn_mfma_f32_16x16x32_bf16(aw[mi], bf, oacc[mi][nt], 0, 0, 0);
        }
    }
    // --- store (single write of out) ---
#pragma unroll
    for (int mi = 0; mi < 4; ++mi) {
        const int c = (wave * 4 + mi) * 16 + quad * 4;
#pragma unroll
        for (int nt = 0; nt < 4; ++nt) {
            const int j = j0 + nt * 16 + l15;
#pragma unroll
            for (int r = 0; r < 4; ++r)
                out[((long)b * 512 + c + r) * 4096 + j] = oacc[mi][nt][r] + co_b[c + r];
        }
    }
}

// ---------------------------------------------------------------------------
// x [B,512,4096] fp32 -> xT [B,4096,512] bf16 (64x64 LDS tile transpose)
// ---------------------------------------------------------------------------
__global__ __launch_bounds__(256) void transpose_x(
    const float* __restrict__ x, unsigned short* __restrict__ xT)
{
    __shared__ unsigned short T[64 * 66];
    const int b  = blockIdx.z;
    const int n0 = blockIdx.x * 64;
    const int c0 = blockIdx.y * 64;
    const int tid = threadIdx.x;
    const int r8 = tid >> 5;
    const int col2 = (tid & 31) * 2;
#pragma unroll
    for (int k = 0; k < 8; ++k) {
        const int c = r8 + k * 8;
        floatx2 v = *(const floatx2*)(x + ((long)(b * 512 + c0 + c)) * 4096 + n0 + col2);
        *(unsigned int*)&T[c * 66 + col2] = pack_bf16(v.x, v.y);
    }
    __syncthreads();
#pragma unroll
    for (int k = 0; k < 8; ++k) {
        const int n = r8 + k * 8;
        unsigned int pk = (unsigned int)T[col2 * 66 + n] | ((unsigned int)T[(col2 + 1) * 66 + n] << 16);
        *(unsigned int*)(xT + ((long)(b * 4096 + n0 + n)) * 512 + c0 + col2) = pk;
    }
}

// ---------------------------------------------------------------------------
// fp32 weights -> bf16, fused layouts:
//  wqkv+wcqck [320][512] = [wq*LOG2E; wk; wcv; wcq; wck],
//  wv [512][512],  wco [512][64].  Biases: [320] = [bq*L; bk; bcv; bcq; bck].
// ---------------------------------------------------------------------------
__global__ __launch_bounds__(256) void convert_weights(
    const float* __restrict__ pq_w, const float* __restrict__ pk_w,
    const float* __restrict__ pv_w, const float* __restrict__ cq_w,
    const float* __restrict__ ck_w, const float* __restrict__ cv_w,
    const float* __restrict__ co_w,
    const float* __restrict__ pq_b, const float* __restrict__ pk_b,
    const float* __restrict__ cv_b, const float* __restrict__ cq_b,
    const float* __restrict__ ck_b,
    unsigned short* __restrict__ dst, float* __restrict__ biases)
{
    const int total = 458752;
    const int gtid = blockIdx.x * 256 + threadIdx.x;
    for (int i = gtid; i < total; i += gridDim.x * 256) {
        float v;
        if (i < 98304) {
            int r = i >> 9, k = i & 511;
            if (r < 64)       v = pq_w[r * 512 + k] * LOG2E;
            else if (r < 128) v = pk_w[(r - 64) * 512 + k];
            else              v = cv_w[(r - 128) * 512 + k];
        } else if (i < 163840) {
            int j = i - 98304; int r = j >> 9, k = j & 511;
            v = (r < 64) ? cq_w[r * 512 + k] : ck_w[(r - 64) * 512 + k];
        } else if (i < 425984) v = pv_w[i - 163840];
        else                   v = co_w[i - 425984];
        dst[i] = f2bf(v);
    }
    if (gtid < 320) {
        float v;
        if (gtid < 64)       v = pq_b[gtid] * LOG2E;
        else if (gtid < 128) v = pk_b[gtid - 64];
        else if (gtid < 192) v = cv_b[gtid - 128];
        else if (gtid < 256) v = cq_b[gtid - 192];
        else                 v = ck_b[gtid - 256];
        biases[gtid] = v;
    }
}

// ---------------------------------------------------------------------------
// channel softmax over q (64 logits, fp32) -> c_attn bf16
// ---------------------------------------------------------------------------
__global__ __launch_bounds__(64) void chan_softmax(
    const float* __restrict__ ce, unsigned short* __restrict__ ca)
{
    const int p = blockIdx.x, b = blockIdx.y, q = threadIdx.x;
    const long base = ((long)b * 64 + p) * 64;
    float v = ce[base + q];
    float m = v;
#pragma unroll
    for (int s = 32; s >= 1; s >>= 1) m = fmaxf(m, __shfl_xor(m, s));
    float e = exp2f((v - m) * LOG2E);
    float sum = e;
#pragma unroll
    for (int s = 32; s >= 1; s >>= 1) sum += __shfl_xor(sum, s);
    ca[base + q] = f2bf(e / sum);
}

// ---------------------------------------------------------------------------
extern "C" void kernel_launch(void* const* d_in, const int* in_sizes, int n_in,
                              void* d_out, int out_size, void* d_ws, size_t ws_size,
                              hipStream_t stream) {
    const float* x    = (const float*)d_in[0];
    const float* pv_b = (const float*)d_in[6];
    const float* co_b = (const float*)d_in[14];
    float* out = (float*)d_out;
    char* ws = (char*)d_ws;

    // ws layout (bytes)
    constexpr long OFF_XT   = 0;                        // bf16 [8][4096][512]
    constexpr long OFF_QKV  = 33554432;                 // bf16 [8][ q_lin | kT(frag) | cvT ] (3 x 262144 shorts)
    constexpr long OFF_VP   = OFF_QKV + 12582912;       // bf16 [8][512][4096] (v * rcp_l, TILED)
    constexpr long OFF_CQCK = OFF_VP + 33554432;        // bf16 [8][128][4096] (cq|ck)
    constexpr long OFF_COT  = OFF_CQCK + 8388608;       // bf16 [8][4096][64]
    constexpr long OFF_RCL  = OFF_COT + 4194304;        // fp32 [8][4096]
    constexpr long OFF_CE   = OFF_RCL + 131072;         // fp32 [8][64][64]
    constexpr long OFF_CAT  = OFF_CE + 131072;          // bf16 [8][64][64]
    constexpr long OFF_WB   = OFF_CAT + 65536;          // bf16 weights (458752)
    constexpr long OFF_BIAS = OFF_WB + 917504;          // fp32 [320]

    unsigned short* xT   = (unsigned short*)(ws + OFF_XT);
    unsigned short* qkvT = (unsigned short*)(ws + OFF_QKV);
    unsigned short* vP   = (unsigned short*)(ws + OFF_VP);
    unsigned short* cqck = (unsigned short*)(ws + OFF_CQCK);
    unsigned short* coT  = (unsigned short*)(ws + OFF_COT);
    float*          rcl  = (float*)(ws + OFF_RCL);
    float*          ce   = (float*)(ws + OFF_CE);
    unsigned short* cat  = (unsigned short*)(ws + OFF_CAT);
    unsigned short* wb   = (unsigned short*)(ws + OFF_WB);
    float*          bias = (float*)(ws + OFF_BIAS);
    unsigned short* wv    = wb + 163840;
    unsigned short* wco   = wb + 425984;

    // 0) convert weights (+bias concat), transpose x
    convert_weights<<<dim3(64), 256, 0, stream>>>(
        (const float*)d_in[1], (const float*)d_in[3], (const float*)d_in[5],
        (const float*)d_in[7], (const float*)d_in[9], (const float*)d_in[11],
        (const float*)d_in[13],
        (const float*)d_in[2], (const float*)d_in[4], (const float*)d_in[12],
        (const float*)d_in[8], (const float*)d_in[10], wb, bias);
    transpose_x<<<dim3(64, 8, 8), 256, 0, stream>>>(x, xT);

    // 1) MERGED projection: [320][512] weights x xT -> q_lin|kT(frag)|cvT + cqck
    tn_gemm<64, 64, true, false, 2><<<dim3(5, 64, 8), 256, 0, stream>>>(
        xT, 512, 2097152L, wb, 512, 0L, qkvT, 192, 786432L,
        cqck, 524288L, nullptr, bias, nullptr, 0L, 512, 1);

    // 2) softmax denominators -> rcp_l (LDS-free frag streaming)
    rowsum_kernel<<<dim3(8, 64), 128, 0, stream>>>(qkvT, rcl);

    // 3) v' = (Wv x + b) * rcp_l  (column scale by position), TILED output
    tn_gemm<128, 128, true, false, 1><<<dim3(32, 4, 8), 256, 0, stream>>>(
        wv, 512, 0L, xT, 512, 2097152L, vP, 4096, 2097152L,
        nullptr, 0L, pv_b, nullptr, rcl, 4096L, 512, 1);

    // 4) channel attention: c_energy (split-K atomic), softmax, c_outT
    hipMemsetAsync(ce, 0, 8 * 64 * 64 * sizeof(float), stream);
    tn_gemm<64, 64, false, true><<<dim3(1, 1, 64), 256, 0, stream>>>(
        cqck, 4096, 524288L, cqck + 262144, 4096, 524288L, ce, 64, 4096L,
        nullptr, 0L, nullptr, nullptr, nullptr, 0L, 512, 8);
    chan_softmax<<<dim3(64, 8), 64, 0, stream>>>(ce, cat);
    tn_gemm<64, 64, true, false><<<dim3(1, 64, 8), 256, 0, stream>>>(
        qkvT + 524288, 64, 786432L, cat, 64, 4096L, coT, 64, 262144L,
        nullptr, 0L, nullptr, nullptr, nullptr, 0L, 64, 1);

    // 5) fused position attention + channel output epilogue -> out (1 write)
    pos_attn_kernel<<<dim3(8, 64), 512, 0, stream>>>(qkvT, vP, wco, coT, co_b, out);
}